// Round 1
// baseline (178.400 us; speedup 1.0000x reference)
//
#include <hip/hip_runtime.h>

// QueryAndGroup: ball query (first 32 idx within radius, index order, padded
// with first hit) + grouped_xyz (xyz[idx]-center) + grouped feature gather.
// Shapes: xyz (8,16384,3) f32, new_xyz (8,1024,3) f32, features (8,64,16384) f32
// Out: (8, 3+64, 1024, 32) f32.

#define BB 8
#define NN 16384
#define SS 1024
#define CC 64
#define NSAMP 32
#define OUTCH (3 + CC)

// radius*radius must be float(0.04) to match the numpy reference's
// weak-scalar promotion (0.039999999f), NOT 0.2f*0.2f (0.040000002f).
#define R2 0.04f

__global__ __launch_bounds__(64) void qg_kernel(
    const float* __restrict__ xyz,      // (B,N,3)
    const float* __restrict__ new_xyz,  // (B,S,3)
    const float* __restrict__ feats,    // (B,C,N)
    float* __restrict__ out)            // (B,67,S,32)
{
    const int bs   = blockIdx.x;
    const int b    = bs >> 10;     // / SS
    const int s    = bs & (SS - 1);
    const int lane = threadIdx.x;  // 0..63

    const float* xb = xyz + (size_t)b * NN * 3;
    const float qx = new_xyz[((size_t)b * SS + s) * 3 + 0];
    const float qy = new_xyz[((size_t)b * SS + s) * 3 + 1];
    const float qz = new_xyz[((size_t)b * SS + s) * 3 + 2];

    __shared__ int sidx[NSAMP];

    int count = 0;
    for (int base = 0; base < NN; base += 64) {
        const int i = base + lane;          // always < NN (NN % 64 == 0)
        const float px = xb[i * 3 + 0];
        const float py = xb[i * 3 + 1];
        const float pz = xb[i * 3 + 2];
        const float dx = qx - px;
        const float dy = qy - py;
        const float dz = qz - pz;
        // numpy order, no FMA contraction: (dx*dx + dy*dy) + dz*dz
        const float d2 = __fadd_rn(__fadd_rn(__fmul_rn(dx, dx),
                                             __fmul_rn(dy, dy)),
                                   __fmul_rn(dz, dz));
        const bool within = d2 < R2;
        const unsigned long long m = __ballot(within);
        if (within) {
            const int pos = count + __popcll(m & ((1ull << lane) - 1ull));
            if (pos < NSAMP) sidx[pos] = i;
        }
        count += __popcll(m);
        if (count >= NSAMP) break;   // wave-uniform
    }
    __syncthreads();

    const int cnt = count < NSAMP ? count : NSAMP;
    const int first = (cnt > 0) ? sidx[0] : 0;
    if (lane < NSAMP && lane >= cnt) sidx[lane] = first;
    __syncthreads();

    // ---- gather phase ----
    const int k    = lane & 31;   // sample slot
    const int half = lane >> 5;   // 0 or 1
    const int idx  = sidx[k];

    // grouped_xyz = xyz[idx] - center  -> channels 0..2
    const size_t obase = (((size_t)b * OUTCH + 0) * SS + s) * NSAMP + k;
    if (half == 0) {
        const float gx = xb[idx * 3 + 0] - qx;
        const float gy = xb[idx * 3 + 1] - qy;
        const float gz = xb[idx * 3 + 2] - qz;
        out[obase + 0 * (size_t)SS * NSAMP] = gx;
        out[obase + 1 * (size_t)SS * NSAMP] = gy;
        out[obase + 2 * (size_t)SS * NSAMP] = gz;
    }

    // grouped features -> channels 3..66; two channels per wave-iteration
    const float* fb = feats + (size_t)b * CC * NN;
    const size_t fo = (((size_t)b * OUTCH + 3) * SS + s) * NSAMP + k;
    for (int c = half; c < CC; c += 2) {
        out[fo + (size_t)c * SS * NSAMP] = fb[(size_t)c * NN + idx];
    }
}

extern "C" void kernel_launch(void* const* d_in, const int* in_sizes, int n_in,
                              void* d_out, int out_size, void* d_ws, size_t ws_size,
                              hipStream_t stream) {
    const float* xyz     = (const float*)d_in[0];
    const float* new_xyz = (const float*)d_in[1];
    const float* feats   = (const float*)d_in[2];
    float* out           = (float*)d_out;

    dim3 grid(BB * SS);
    dim3 block(64);
    qg_kernel<<<grid, block, 0, stream>>>(xyz, new_xyz, feats, out);
}

// Round 2
// 158.635 us; speedup vs baseline: 1.1246x; 1.1246x over previous
//
#include <hip/hip_runtime.h>

// QueryAndGroup: ball query (first 32 idx within radius, index order, padded
// with first hit) + grouped_xyz (xyz[idx]-center) + grouped feature gather.
// Shapes: xyz (8,16384,3) f32, new_xyz (8,1024,3) f32, features (8,64,16384) f32
// Out: (8, 3+64, 1024, 32) f32.
//
// R2 structure: (A) transpose feats to (B,N,C) so each sample's channels are a
// contiguous 256B row + ball query writing idx & grouped_xyz; (B) gather via
// LDS with coalesced reads AND coalesced writes. R1's scattered 4B gather was
// latency/L1-line bound (1.07 GB of line traffic, 13% HBM BW).

#define BB 8
#define NN 16384
#define SS 1024
#define CC 64
#define NSAMP 32
#define OUTCH (3 + CC)

// float(0.04) to match numpy's weak-scalar promotion (NOT 0.2f*0.2f).
#define R2 0.04f

// ---------------- merged kernel A: transpose + ball query ----------------
// blocks [0, 2048): transpose one (b, 64-channel, 64-point) tile
// blocks [2048, 4096): 4 ball queries (one per wave)
__global__ __launch_bounds__(256) void prep_kernel(
    const float* __restrict__ xyz,      // (B,N,3)
    const float* __restrict__ new_xyz,  // (B,S,3)
    const float* __restrict__ feats,    // (B,C,N)
    float* __restrict__ ftr,            // ws: (B,N,C)
    int* __restrict__ idxq,             // ws: (B*S,32)
    float* __restrict__ out)            // (B,67,S,32)
{
    const int t = threadIdx.x;
    if (blockIdx.x < 2048) {
        // ---- transpose (B,C,N) -> (B,N,C) ----
        const int blk = blockIdx.x;
        const int b  = blk >> 8;            // / (N/64)
        const int n0 = (blk & 255) << 6;
        __shared__ float tile[64][65];
        const int nl = t & 63;
        const int cq = t >> 6;              // 0..3 (one channel per wave/iter)
        const float* fb = feats + (size_t)b * CC * NN;
        #pragma unroll
        for (int ci = 0; ci < 16; ++ci) {
            const int c = ci * 4 + cq;
            tile[nl][c] = fb[(size_t)c * NN + n0 + nl];   // 256B coalesced
        }
        __syncthreads();
        float* ob = ftr + ((size_t)b * NN + n0) * CC;
        #pragma unroll
        for (int ni = 0; ni < 16; ++ni) {
            const int n = ni * 4 + cq;
            ob[(size_t)n * CC + nl] = tile[n][nl];        // 256B coalesced
        }
    } else {
        // ---- ball query: 4 waves, one query each ----
        const int wave = t >> 6;
        const int lane = t & 63;
        const int q    = (blockIdx.x - 2048) * 4 + wave;  // 0..8191
        const int b    = q >> 10;
        const int s    = q & (SS - 1);

        const float* xb = xyz + (size_t)b * NN * 3;
        const float qx = new_xyz[((size_t)b * SS + s) * 3 + 0];
        const float qy = new_xyz[((size_t)b * SS + s) * 3 + 1];
        const float qz = new_xyz[((size_t)b * SS + s) * 3 + 2];

        __shared__ int sidx[4][NSAMP];

        int count = 0;
        for (int base = 0; base < NN; base += 64) {
            const int i = base + lane;
            const float px = xb[i * 3 + 0];
            const float py = xb[i * 3 + 1];
            const float pz = xb[i * 3 + 2];
            const float dx = qx - px;
            const float dy = qy - py;
            const float dz = qz - pz;
            // numpy order, no FMA contraction
            const float d2 = __fadd_rn(__fadd_rn(__fmul_rn(dx, dx),
                                                 __fmul_rn(dy, dy)),
                                       __fmul_rn(dz, dz));
            const bool within = d2 < R2;
            const unsigned long long m = __ballot(within);
            if (within) {
                const int pos = count + __popcll(m & ((1ull << lane) - 1ull));
                if (pos < NSAMP) sidx[wave][pos] = i;
            }
            count += __popcll(m);
            if (count >= NSAMP) break;   // wave-uniform
        }
        __syncthreads();
        const int cnt = count < NSAMP ? count : NSAMP;
        const int first = (cnt > 0) ? sidx[wave][0] : 0;
        if (lane < NSAMP && lane >= cnt) sidx[wave][lane] = first;
        __syncthreads();

        if (lane < NSAMP) {
            const int k = lane;
            const int idx = sidx[wave][k];
            idxq[(size_t)q * NSAMP + k] = idx;
            // grouped_xyz -> out channels 0..2
            const float gx = xb[idx * 3 + 0] - qx;
            const float gy = xb[idx * 3 + 1] - qy;
            const float gz = xb[idx * 3 + 2] - qz;
            const size_t o = (((size_t)b * OUTCH + 0) * SS + s) * NSAMP + k;
            out[o + 0 * (size_t)SS * NSAMP] = gx;
            out[o + 1 * (size_t)SS * NSAMP] = gy;
            out[o + 2 * (size_t)SS * NSAMP] = gz;
        }
    }
}

// ---------------- kernel B: coalesced gather via LDS ----------------
__global__ __launch_bounds__(256) void gather_kernel(
    const float* __restrict__ ftr,      // (B,N,C)
    const int*   __restrict__ idxq,     // (B*S,32)
    float* __restrict__ out)            // (B,67,S,32)
{
    const int q = blockIdx.x;           // b*S+s
    const int b = q >> 10;
    const int s = q & (SS - 1);
    const int t = threadIdx.x;

    __shared__ int   sidx[NSAMP];
    __shared__ float f[NSAMP][CC + 1];  // +1 pad: conflict-free both phases

    if (t < NSAMP) sidx[t] = idxq[(size_t)q * NSAMP + t];
    __syncthreads();

    // stage: 4 samples/iter, each wave reads one 256B contiguous row
    const int c  = t & 63;
    const int kq = t >> 6;              // 0..3
    const float* fb = ftr + (size_t)b * NN * CC;
    #pragma unroll
    for (int kk = 0; kk < 8; ++kk) {
        const int k = kk * 4 + kq;
        f[k][c] = fb[(size_t)sidx[k] * CC + c];
    }
    __syncthreads();

    // write: channel-major, 128B coalesced segments per channel
    const int k2 = t & 31;
    const int c2 = t >> 5;              // 0..7
    const size_t ob = (((size_t)b * OUTCH + 3) * SS + s) * NSAMP + k2;
    #pragma unroll
    for (int ci = 0; ci < 8; ++ci) {
        const int cc = ci * 8 + c2;
        out[ob + (size_t)cc * SS * NSAMP] = f[k2][cc];
    }
}

// ---------------- fallback: R1 fused kernel (if ws too small) ----------------
__global__ __launch_bounds__(64) void qg_fused(
    const float* __restrict__ xyz, const float* __restrict__ new_xyz,
    const float* __restrict__ feats, float* __restrict__ out)
{
    const int bs   = blockIdx.x;
    const int b    = bs >> 10;
    const int s    = bs & (SS - 1);
    const int lane = threadIdx.x;

    const float* xb = xyz + (size_t)b * NN * 3;
    const float qx = new_xyz[((size_t)b * SS + s) * 3 + 0];
    const float qy = new_xyz[((size_t)b * SS + s) * 3 + 1];
    const float qz = new_xyz[((size_t)b * SS + s) * 3 + 2];

    __shared__ int sidx[NSAMP];
    int count = 0;
    for (int base = 0; base < NN; base += 64) {
        const int i = base + lane;
        const float dx = qx - xb[i * 3 + 0];
        const float dy = qy - xb[i * 3 + 1];
        const float dz = qz - xb[i * 3 + 2];
        const float d2 = __fadd_rn(__fadd_rn(__fmul_rn(dx, dx),
                                             __fmul_rn(dy, dy)),
                                   __fmul_rn(dz, dz));
        const bool within = d2 < R2;
        const unsigned long long m = __ballot(within);
        if (within) {
            const int pos = count + __popcll(m & ((1ull << lane) - 1ull));
            if (pos < NSAMP) sidx[pos] = i;
        }
        count += __popcll(m);
        if (count >= NSAMP) break;
    }
    __syncthreads();
    const int cnt = count < NSAMP ? count : NSAMP;
    const int first = (cnt > 0) ? sidx[0] : 0;
    if (lane < NSAMP && lane >= cnt) sidx[lane] = first;
    __syncthreads();

    const int k    = lane & 31;
    const int half = lane >> 5;
    const int idx  = sidx[k];
    const size_t obase = (((size_t)b * OUTCH + 0) * SS + s) * NSAMP + k;
    if (half == 0) {
        out[obase + 0 * (size_t)SS * NSAMP] = xb[idx * 3 + 0] - qx;
        out[obase + 1 * (size_t)SS * NSAMP] = xb[idx * 3 + 1] - qy;
        out[obase + 2 * (size_t)SS * NSAMP] = xb[idx * 3 + 2] - qz;
    }
    const float* fb = feats + (size_t)b * CC * NN;
    const size_t fo = (((size_t)b * OUTCH + 3) * SS + s) * NSAMP + k;
    for (int cch = half; cch < CC; cch += 2) {
        out[fo + (size_t)cch * SS * NSAMP] = fb[(size_t)cch * NN + idx];
    }
}

extern "C" void kernel_launch(void* const* d_in, const int* in_sizes, int n_in,
                              void* d_out, int out_size, void* d_ws, size_t ws_size,
                              hipStream_t stream) {
    const float* xyz     = (const float*)d_in[0];
    const float* new_xyz = (const float*)d_in[1];
    const float* feats   = (const float*)d_in[2];
    float* out           = (float*)d_out;

    const size_t ftr_bytes = (size_t)BB * NN * CC * sizeof(float);      // 33.5 MB
    const size_t idx_bytes = (size_t)BB * SS * NSAMP * sizeof(int);     // 1 MB

    if (ws_size >= ftr_bytes + idx_bytes) {
        float* ftr = (float*)d_ws;
        int* idxq  = (int*)((char*)d_ws + ftr_bytes);
        prep_kernel<<<4096, 256, 0, stream>>>(xyz, new_xyz, feats, ftr, idxq, out);
        gather_kernel<<<BB * SS, 256, 0, stream>>>(ftr, idxq, out);
    } else {
        qg_fused<<<BB * SS, 64, 0, stream>>>(xyz, new_xyz, feats, out);
    }
}

// Round 3
// 120.051 us; speedup vs baseline: 1.4860x; 1.3214x over previous
//
#include <hip/hip_runtime.h>

// QueryAndGroup: ball query (first 32 idx within radius, index order, padded
// with first hit) + grouped_xyz (xyz[idx]-center) + grouped feature gather.
// Shapes: xyz (8,16384,3) f32, new_xyz (8,1024,3) f32, features (8,64,16384) f32
// Out: (8, 3+64, 1024, 32) f32.
//
// R3: (a) ball-query scan chunked 512 pts/iter with all loads issued before
// the ballot phase -> one memory latency per chunk instead of per 64 pts
// (R2's prep was latency-serialized, 70us @ 790 GB/s, VALUBusy 7.7%);
// (b) float4 transpose both global sides; (c) float4 gather both phases.
// LDS pads of +1 keep all patterns <=2-way (free on gfx950, m136).

#define BB 8
#define NN 16384
#define SS 1024
#define CC 64
#define NSAMP 32
#define OUTCH (3 + CC)

// float(0.04) to match numpy's weak-scalar promotion (NOT 0.2f*0.2f).
#define R2 0.04f

// ---------------- merged kernel A: transpose + ball query ----------------
// blocks [0, 2048): transpose one (b, 64ch, 64pt) tile of feats -> (B,N,C)
// blocks [2048, 4096): 4 ball queries (one per wave)
__global__ __launch_bounds__(256) void prep_kernel(
    const float* __restrict__ xyz,      // (B,N,3)
    const float* __restrict__ new_xyz,  // (B,S,3)
    const float* __restrict__ feats,    // (B,C,N)
    float* __restrict__ ftr,            // ws: (B,N,C)
    int* __restrict__ idxq,             // ws: (B*S,32)
    float* __restrict__ out)            // (B,67,S,32)
{
    __shared__ float tile[64][65];      // transpose tile (65-pad: 2-way max)
    __shared__ int sidx[4][NSAMP];

    const int t = threadIdx.x;
    if (blockIdx.x < 2048) {
        // ---- transpose (B,C,N) -> (B,N,C), float4 on both global sides ----
        const int blk = blockIdx.x;
        const int b  = blk >> 8;            // / (N/64)
        const int n0 = (blk & 255) << 6;
        const float* fb = feats + (size_t)b * CC * NN + n0;
        // read: 16 lanes cover one channel row (16 x float4 = 256B)
        {
            const int c0 = t >> 4;          // 0..15
            const int nq = (t & 15) * 4;
            #pragma unroll
            for (int pass = 0; pass < 4; ++pass) {
                const int c = c0 + pass * 16;
                const float4 v = *(const float4*)(fb + (size_t)c * NN + nq);
                tile[nq + 0][c] = v.x;
                tile[nq + 1][c] = v.y;
                tile[nq + 2][c] = v.z;
                tile[nq + 3][c] = v.w;
            }
        }
        __syncthreads();
        // write: 16 lanes cover one point row (16 x float4 = 256B)
        {
            float* ob = ftr + ((size_t)b * NN + n0) * CC;
            const int nb = t >> 4;          // 0..15
            const int c4 = (t & 15) * 4;
            #pragma unroll
            for (int pass = 0; pass < 4; ++pass) {
                const int n = nb + pass * 16;
                float4 v;
                v.x = tile[n][c4 + 0];
                v.y = tile[n][c4 + 1];
                v.z = tile[n][c4 + 2];
                v.w = tile[n][c4 + 3];
                *(float4*)(ob + (size_t)n * CC + c4) = v;
            }
        }
    } else {
        // ---- ball query: 4 waves, one query each, 512-pt chunks ----
        const int wave = t >> 6;
        const int lane = t & 63;
        const int q    = (blockIdx.x - 2048) * 4 + wave;  // 0..8191
        const int b    = q >> 10;
        const int s    = q & (SS - 1);

        const float* xb = xyz + (size_t)b * NN * 3;
        const float qx = new_xyz[((size_t)b * SS + s) * 3 + 0];
        const float qy = new_xyz[((size_t)b * SS + s) * 3 + 1];
        const float qz = new_xyz[((size_t)b * SS + s) * 3 + 2];
        const unsigned long long below = (1ull << lane) - 1ull;

        int count = 0;
        for (int base = 0; base < NN; base += 512) {
            float d2[8];
            #pragma unroll
            for (int j = 0; j < 8; ++j) {
                const int i = base + j * 64 + lane;
                const float dx = qx - xb[i * 3 + 0];
                const float dy = qy - xb[i * 3 + 1];
                const float dz = qz - xb[i * 3 + 2];
                // numpy order, no FMA contraction
                d2[j] = __fadd_rn(__fadd_rn(__fmul_rn(dx, dx),
                                            __fmul_rn(dy, dy)),
                                  __fmul_rn(dz, dz));
            }
            #pragma unroll
            for (int j = 0; j < 8; ++j) {
                const bool within = d2[j] < R2;
                const unsigned long long m = __ballot(within);
                if (within) {
                    const int pos = count + __popcll(m & below);
                    if (pos < NSAMP) sidx[wave][pos] = base + j * 64 + lane;
                }
                count += __popcll(m);
            }
            if (count >= NSAMP) break;   // wave-uniform
        }
        __syncthreads();
        const int cnt = count < NSAMP ? count : NSAMP;
        const int first = (cnt > 0) ? sidx[wave][0] : 0;
        if (lane < NSAMP && lane >= cnt) sidx[wave][lane] = first;
        __syncthreads();

        if (lane < NSAMP) {
            const int k = lane;
            const int idx = sidx[wave][k];
            idxq[(size_t)q * NSAMP + k] = idx;
            // grouped_xyz -> out channels 0..2
            const float gx = xb[idx * 3 + 0] - qx;
            const float gy = xb[idx * 3 + 1] - qy;
            const float gz = xb[idx * 3 + 2] - qz;
            const size_t o = (((size_t)b * OUTCH + 0) * SS + s) * NSAMP + k;
            out[o + 0 * (size_t)SS * NSAMP] = gx;
            out[o + 1 * (size_t)SS * NSAMP] = gy;
            out[o + 2 * (size_t)SS * NSAMP] = gz;
        }
    }
}

// ---------------- kernel B: coalesced gather via LDS, float4 ----------------
__global__ __launch_bounds__(256) void gather_kernel(
    const float* __restrict__ ftr,      // (B,N,C)
    const int*   __restrict__ idxq,     // (B*S,32)
    float* __restrict__ out)            // (B,67,S,32)
{
    const int q = blockIdx.x;           // b*S+s
    const int b = q >> 10;
    const int s = q & (SS - 1);
    const int t = threadIdx.x;

    __shared__ int   sidx[NSAMP];
    __shared__ float f[NSAMP][CC + 1];  // 65-pad: <=2-way banks (free)

    if (t < NSAMP) sidx[t] = idxq[(size_t)q * NSAMP + t];
    __syncthreads();

    // stage: 16 lanes per sample row, float4 reads (256B per row)
    {
        const float* fb = ftr + (size_t)b * NN * CC;
        const int k0 = t >> 4;          // 0..15
        const int c4 = (t & 15) * 4;
        #pragma unroll
        for (int pass = 0; pass < 2; ++pass) {
            const int k = k0 + pass * 16;
            const float4 v = *(const float4*)(fb + (size_t)sidx[k] * CC + c4);
            f[k][c4 + 0] = v.x;
            f[k][c4 + 1] = v.y;
            f[k][c4 + 2] = v.z;
            f[k][c4 + 3] = v.w;
        }
    }
    __syncthreads();

    // write: lane handles float4 of samples; 8 lanes per channel (128B),
    // 32 channels per pass -> 1KB per wave-instr
    {
        const int k4 = (t & 7) * 4;
        const int c0 = t >> 3;          // 0..31
        #pragma unroll
        for (int pass = 0; pass < 2; ++pass) {
            const int c = c0 + pass * 32;
            float4 v;
            v.x = f[k4 + 0][c];
            v.y = f[k4 + 1][c];
            v.z = f[k4 + 2][c];
            v.w = f[k4 + 3][c];
            *(float4*)(out + (((size_t)b * OUTCH + 3 + c) * SS + s) * NSAMP + k4) = v;
        }
    }
}

// ---------------- fallback: R1 fused kernel (if ws too small) ----------------
__global__ __launch_bounds__(64) void qg_fused(
    const float* __restrict__ xyz, const float* __restrict__ new_xyz,
    const float* __restrict__ feats, float* __restrict__ out)
{
    const int bs   = blockIdx.x;
    const int b    = bs >> 10;
    const int s    = bs & (SS - 1);
    const int lane = threadIdx.x;

    const float* xb = xyz + (size_t)b * NN * 3;
    const float qx = new_xyz[((size_t)b * SS + s) * 3 + 0];
    const float qy = new_xyz[((size_t)b * SS + s) * 3 + 1];
    const float qz = new_xyz[((size_t)b * SS + s) * 3 + 2];

    __shared__ int sidx[NSAMP];
    int count = 0;
    for (int base = 0; base < NN; base += 64) {
        const int i = base + lane;
        const float dx = qx - xb[i * 3 + 0];
        const float dy = qy - xb[i * 3 + 1];
        const float dz = qz - xb[i * 3 + 2];
        const float d2 = __fadd_rn(__fadd_rn(__fmul_rn(dx, dx),
                                             __fmul_rn(dy, dy)),
                                   __fmul_rn(dz, dz));
        const bool within = d2 < R2;
        const unsigned long long m = __ballot(within);
        if (within) {
            const int pos = count + __popcll(m & ((1ull << lane) - 1ull));
            if (pos < NSAMP) sidx[pos] = i;
        }
        count += __popcll(m);
        if (count >= NSAMP) break;
    }
    __syncthreads();
    const int cnt = count < NSAMP ? count : NSAMP;
    const int first = (cnt > 0) ? sidx[0] : 0;
    if (lane < NSAMP && lane >= cnt) sidx[lane] = first;
    __syncthreads();

    const int k    = lane & 31;
    const int half = lane >> 5;
    const int idx  = sidx[k];
    const size_t obase = (((size_t)b * OUTCH + 0) * SS + s) * NSAMP + k;
    if (half == 0) {
        out[obase + 0 * (size_t)SS * NSAMP] = xb[idx * 3 + 0] - qx;
        out[obase + 1 * (size_t)SS * NSAMP] = xb[idx * 3 + 1] - qy;
        out[obase + 2 * (size_t)SS * NSAMP] = xb[idx * 3 + 2] - qz;
    }
    const float* fb = feats + (size_t)b * CC * NN;
    const size_t fo = (((size_t)b * OUTCH + 3) * SS + s) * NSAMP + k;
    for (int cch = half; cch < CC; cch += 2) {
        out[fo + (size_t)cch * SS * NSAMP] = fb[(size_t)cch * NN + idx];
    }
}

extern "C" void kernel_launch(void* const* d_in, const int* in_sizes, int n_in,
                              void* d_out, int out_size, void* d_ws, size_t ws_size,
                              hipStream_t stream) {
    const float* xyz     = (const float*)d_in[0];
    const float* new_xyz = (const float*)d_in[1];
    const float* feats   = (const float*)d_in[2];
    float* out           = (float*)d_out;

    const size_t ftr_bytes = (size_t)BB * NN * CC * sizeof(float);      // 33.5 MB
    const size_t idx_bytes = (size_t)BB * SS * NSAMP * sizeof(int);     // 1 MB

    if (ws_size >= ftr_bytes + idx_bytes) {
        float* ftr = (float*)d_ws;
        int* idxq  = (int*)((char*)d_ws + ftr_bytes);
        prep_kernel<<<4096, 256, 0, stream>>>(xyz, new_xyz, feats, ftr, idxq, out);
        gather_kernel<<<BB * SS, 256, 0, stream>>>(ftr, idxq, out);
    } else {
        qg_fused<<<BB * SS, 64, 0, stream>>>(xyz, new_xyz, feats, out);
    }
}